// Round 5
// baseline (96.892 us; speedup 1.0000x reference)
//
#include <hip/hip_runtime.h>
#include <stdint.h>

#define H_HEADS 16
#define ADIM    128
#define SLEN    2048
#define DMODEL  2048

typedef __attribute__((ext_vector_type(8))) short  short8;   // bf16x8 MFMA frag
typedef __attribute__((ext_vector_type(4))) float  float4v;  // fp32x4 MFMA acc
typedef __attribute__((ext_vector_type(4))) unsigned short ushort4v;

typedef const __attribute__((address_space(1))) unsigned int gas_u32;
typedef __attribute__((address_space(3))) unsigned int las_u32;

union F4 { float4 v; float a[4]; };
union PU { unsigned u[4]; short8 s; };

__device__ __forceinline__ unsigned short f2bf(float f) {
  union { float f; unsigned u; } v; v.f = f;
  unsigned r = v.u + 0x7FFFu + ((v.u >> 16) & 1u);   // RNE
  return (unsigned short)(r >> 16);
}

__device__ __forceinline__ unsigned cvt_pk_bf16(float lo, float hi) {
  unsigned r;
  asm("v_cvt_pk_bf16_f32 %0, %1, %2" : "=v"(r) : "v"(lo), "v"(hi));
  return r;
}

// after p32+p16 swap: a = [x@r0, x@r2, y@r0, y@r2], b = [x@r1, x@r3, y@r1, y@r3]
__device__ __forceinline__ void xswap(unsigned& a, unsigned& b) {
  asm volatile("v_permlane32_swap_b32 %0, %1" : "+v"(a), "+v"(b));
  asm volatile("v_permlane16_swap_b32 %0, %1" : "+v"(a), "+v"(b));
}

__device__ __forceinline__ float fsin01(float r) { float o; asm("v_sin_f32 %0, %1" : "=v"(o) : "v"(r)); return o; }
__device__ __forceinline__ float fcos01(float r) { float o; asm("v_cos_f32 %0, %1" : "=v"(o) : "v"(r)); return o; }
__device__ __forceinline__ float ffract(float x) { float o; asm("v_fract_f32 %0, %1" : "=v"(o) : "v"(x)); return o; }

// log2(10000)/64
#define ROPE_C 0.20762050593045935f
// log2(1/(2*pi))
#define L2I2PI -2.651496129472319f
// (1/sqrt(128)) * log2(e)
#define C2LOG  0.12751879523103988f
// defer-max threshold (log2 units ~ 8 nats)
#define THRZ   11.0f

// ---------------- prep_k: RoPE(K) -> bf16, [B*H][S][128], chunk ^= (s&7)
__global__ __launch_bounds__(256) void prep_k(const float* __restrict__ xk,
                                              unsigned short* __restrict__ kw) {
  int t = blockIdx.x * 256 + threadIdx.x;
  int i4 = t & 15;
  int h  = (t >> 4) & (H_HEADS - 1);
  int s  = (t >> 8) & (SLEN - 1);
  int b  = t >> 19;
  int i0 = i4 * 4;
  long ib = ((long)(b * SLEN + s)) * DMODEL + h * ADIM;
  F4 x1, x2;
  x1.v = *(const float4*)(xk + ib + i0);
  x2.v = *(const float4*)(xk + ib + i0 + 64);
  ushort4v o1, o2;
  #pragma unroll
  for (int j = 0; j < 4; ++j) {
    float rev = (float)s * exp2f(fmaf(-(float)(i0 + j), ROPE_C, L2I2PI));
    float r = ffract(rev);
    float sn = fsin01(r), cs = fcos01(r);
    o1[j] = f2bf( x1.a[j] * cs + x2.a[j] * sn);
    o2[j] = f2bf(-x1.a[j] * sn + x2.a[j] * cs);
  }
  long row = ((long)((b * H_HEADS + h) * SLEN + s)) * ADIM;
  int swz = s & 7;
  int c1 = ((((i0     ) >> 3) ^ swz) << 3) | (i0 & 7);
  int c2 = ((((i0 + 64) >> 3) ^ swz) << 3) | (i0 & 7);
  *(ushort4v*)(kw + row + c1) = o1;
  *(ushort4v*)(kw + row + c2) = o2;
}

// ---------------- prep_v: transpose V per 32-key tile -> bf16
// layout [B*H][tile=64][d=128][key=32], 16B-chunk swizzle: chunk(0..3) ^= (d&3)
__global__ __launch_bounds__(256) void prep_v(const float* __restrict__ xv,
                                              unsigned short* __restrict__ vw) {
  __shared__ float lv[32 * 129];
  int jt = blockIdx.x;            // 0..63
  int bh = blockIdx.y;
  int b = bh >> 4, h = bh & (H_HEADS - 1);
  int t = threadIdx.x;
  #pragma unroll
  for (int it = 0; it < 4; ++it) {            // 1024 float4 reads
    int id  = it * 256 + t;
    int row = id >> 5;                        // 0..31 (key within tile)
    int c4  = (id & 31) * 4;                  // d chunk
    F4 x;
    x.v = *(const float4*)(xv + ((long)(b * SLEN + jt * 32 + row)) * DMODEL + h * ADIM + c4);
    #pragma unroll
    for (int j = 0; j < 4; ++j) lv[row * 129 + c4 + j] = x.a[j];
  }
  __syncthreads();
  unsigned short* vt = vw + ((long)(bh * 64 + jt)) * 4096;   // [128][32]
  #pragma unroll
  for (int it = 0; it < 4; ++it) {            // 1024 ushort4 writes
    int id = it * 256 + t;
    int d  = id >> 3;                         // 0..127
    int i  = id & 7;                          // key group: keys 4i..4i+3
    ushort4v o;
    #pragma unroll
    for (int j = 0; j < 4; ++j) o[j] = f2bf(lv[(4 * i + j) * 129 + d]);
    int off = d * 32 + ((((i >> 1) ^ (d & 3)) << 3) | ((i & 1) << 2));
    *(ushort4v*)(vt + off) = o;
  }
}

// ---------------- fused causal flash attention, 1 q-tile(64)/block, KVBLK=32
__global__ __launch_bounds__(256, 4) void attn_fwd(const float* __restrict__ xq,
                                                   const unsigned short* __restrict__ kw,
                                                   const unsigned short* __restrict__ vw,
                                                   float* __restrict__ out) {
  __shared__ __align__(16) unsigned short kL[2][32 * 128];   // 2 x 8KB
  __shared__ __align__(16) unsigned short vL[2][128 * 32];   // 2 x 8KB

  int n  = blockIdx.x;                  // 1024 blocks, qt-descending dispatch
  int qt = 31 - (n >> 5);
  int bh = n & 31;
  int b = bh >> 4, h = bh & (H_HEADS - 1);
  int t = threadIdx.x, l = t & 63, w = t >> 6;
  int lq = l & 15, g = l >> 4, lq7 = lq & 7, lq3 = lq & 3;
  int sq = qt * 64 + w * 16 + lq;       // this lane's q row

  // ---- Q: load fp32, RoPE in-register (hw sin/cos), pack bf16 frags
  const float* qsrc = xq + ((long)(b * SLEN + sq)) * DMODEL + h * ADIM;
  float q32[4][8];
  #pragma unroll
  for (int c = 0; c < 4; ++c) {
    F4 lo, hi;
    lo.v = *(const float4*)(qsrc + c * 32 + g * 8);
    hi.v = *(const float4*)(qsrc + c * 32 + g * 8 + 4);
    #pragma unroll
    for (int j = 0; j < 4; ++j) { q32[c][j] = lo.a[j]; q32[c][j + 4] = hi.a[j]; }
  }
  short8 qf[4];
  #pragma unroll
  for (int c = 0; c < 2; ++c) {
    #pragma unroll
    for (int j = 0; j < 8; ++j) {
      int a = c * 32 + g * 8 + j;
      float rev = (float)sq * exp2f(fmaf(-(float)a, ROPE_C, L2I2PI));
      float r = ffract(rev);
      float sn = fsin01(r), cs = fcos01(r);
      qf[c    ][j] = (short)f2bf( q32[c][j] * cs + q32[c + 2][j] * sn);
      qf[c + 2][j] = (short)f2bf(-q32[c][j] * sn + q32[c + 2][j] * cs);
    }
  }

  float4v acc[8];
  #pragma unroll
  for (int i = 0; i < 8; ++i) acc[i] = (float4v){0.f, 0.f, 0.f, 0.f};
  float m_z = -1e30f, l_run = 0.f;

  const unsigned short* kbase_g = kw + (long)bh * SLEN * ADIM;
  const unsigned short* vbase_g = vw + (long)bh * 64 * 4096;

  auto STAGE = [&](int bufi, int jn) {         // 8KB K + 8KB V, per wave 2+2 insts
    const unsigned short* ks = kbase_g + (long)jn * (32 * ADIM);
    const unsigned short* vs = vbase_g + (long)jn * 4096;
    #pragma unroll
    for (int i = 0; i < 2; ++i) {
      int seg = w * 2 + i;                     // 0..7, 512 ushorts each
      __builtin_amdgcn_global_load_lds((gas_u32*)(ks + seg * 512 + l * 8),
                                       (las_u32*)&kL[bufi][seg * 512], 16, 0, 0);
      __builtin_amdgcn_global_load_lds((gas_u32*)(vs + seg * 512 + l * 8),
                                       (las_u32*)&vL[bufi][seg * 512], 16, 0, 0);
    }
  };

  int nt = 2 * qt + 2;

  // ---- prologue
  STAGE(0, 0);
  asm volatile("s_waitcnt vmcnt(0)" ::: "memory");
  __builtin_amdgcn_s_barrier();
  int cur = 0;

  for (int jt = 0; jt < nt; ++jt) {
    if (jt < nt - 1) STAGE(cur ^ 1, jt + 1);

    // ---- swapped QK^T: S^T[key32][q16] = K · Q^T
    float4v sv[2];
    sv[0] = (float4v){0.f, 0.f, 0.f, 0.f};
    sv[1] = (float4v){0.f, 0.f, 0.f, 0.f};
    const unsigned short* kl = &kL[cur][0];
    __builtin_amdgcn_s_setprio(1);
    #pragma unroll
    for (int c = 0; c < 4; ++c) {
      int koff = ((c * 4 + g) ^ lq7) << 3;
      #pragma unroll
      for (int kb = 0; kb < 2; ++kb) {
        short8 kf = *(const short8*)&kl[(kb * 16 + lq) * 128 + koff];
        sv[kb] = __builtin_amdgcn_mfma_f32_16x16x32_bf16(kf, qf[c], sv[kb], 0, 0, 0);
      }
    }
    __builtin_amdgcn_s_setprio(0);

    // ---- mask + log2-domain online softmax (8 scores of row lq)
    float s[8];
    #pragma unroll
    for (int kb = 0; kb < 2; ++kb)
      #pragma unroll
      for (int r = 0; r < 4; ++r) s[kb * 4 + r] = sv[kb][r];
    if (jt >= 2 * qt) {                        // diagonal tiles
      #pragma unroll
      for (int kb = 0; kb < 2; ++kb)
        #pragma unroll
        for (int r = 0; r < 4; ++r)
          if (jt * 32 + kb * 16 + g * 4 + r > sq) s[kb * 4 + r] = -1e30f;
    }
    float t0 = fmaxf(fmaxf(s[0], s[1]), fmaxf(s[2], s[3]));
    float t1 = fmaxf(fmaxf(s[4], s[5]), fmaxf(s[6], s[7]));
    float tm = fmaxf(t0, t1);
    tm = fmaxf(tm, __shfl_xor(tm, 16));
    tm = fmaxf(tm, __shfl_xor(tm, 32));
    float zt = tm * C2LOG;
    if (!__all(zt <= m_z + THRZ)) {            // defer-max rescale (rare)
      float mn = fmaxf(m_z, zt);
      float corr = exp2f(m_z - mn);
      m_z = mn;
      l_run *= corr;
      float cb[4];
      #pragma unroll
      for (int r = 0; r < 4; ++r) cb[r] = __shfl(corr, g * 4 + r);
      #pragma unroll
      for (int db = 0; db < 8; ++db)
        #pragma unroll
        for (int r = 0; r < 4; ++r) acc[db][r] *= cb[r];
    }
    float p[8];
    float ts = 0.f;
    #pragma unroll
    for (int i = 0; i < 8; ++i) { p[i] = exp2f(fmaf(s[i], C2LOG, -m_z)); ts += p[i]; }
    l_run += ts;

    // ---- P -> bf16 A-frag in-register (cvt_pk + permlane)
    unsigned L0 = cvt_pk_bf16(p[0], p[1]);
    unsigned H0 = cvt_pk_bf16(p[2], p[3]);
    unsigned L1 = cvt_pk_bf16(p[4], p[5]);
    unsigned H1 = cvt_pk_bf16(p[6], p[7]);
    xswap(L0, L1);
    xswap(H0, H1);
    PU pa;
    pa.u[0] = L0; pa.u[1] = H0; pa.u[2] = L1; pa.u[3] = H1;

    // ---- PV: O[q16][d128] += P · V
    const unsigned short* vl = &vL[cur][0];
    __builtin_amdgcn_s_setprio(1);
    #pragma unroll
    for (int db = 0; db < 8; ++db) {
      int ch = (g ^ lq3) << 3;                 // d&3 == lq&3
      short8 vb = *(const short8*)&vl[(db * 16 + lq) * 32 + ch];
      acc[db] = __builtin_amdgcn_mfma_f32_16x16x32_bf16(pa.s, vb, acc[db], 0, 0, 0);
    }
    __builtin_amdgcn_s_setprio(0);

    asm volatile("s_waitcnt vmcnt(0)" ::: "memory");
    __builtin_amdgcn_s_barrier();
    cur ^= 1;
  }

  // ---- epilogue: normalize and store fp32
  float lt = l_run + __shfl_xor(l_run, 16);
  lt += __shfl_xor(lt, 32);
  float linv = 1.0f / lt;
  float lb[4];
  #pragma unroll
  for (int r = 0; r < 4; ++r) lb[r] = __shfl(linv, g * 4 + r);
  #pragma unroll
  for (int db = 0; db < 8; ++db)
    #pragma unroll
    for (int r = 0; r < 4; ++r)
      out[((long)(b * SLEN + qt * 64 + w * 16 + g * 4 + r)) * DMODEL + h * ADIM + db * 16 + lq]
        = acc[db][r] * lb[r];
}

extern "C" void kernel_launch(void* const* d_in, const int* in_sizes, int n_in,
                              void* d_out, int out_size, void* d_ws, size_t ws_size,
                              hipStream_t stream) {
  const float* xq = (const float*)d_in[0];
  const float* xk = (const float*)d_in[1];
  const float* xv = (const float*)d_in[2];
  float* outp = (float*)d_out;
  int B = in_sizes[0] / (SLEN * DMODEL);                    // 2
  size_t perT = (size_t)B * H_HEADS * SLEN * ADIM;          // bf16 elems per tensor
  unsigned short* kw = (unsigned short*)d_ws;               // 16.78 MB
  unsigned short* vw = kw + perT;                           // 16.78 MB (total ~33.6 MB ws)

  prep_k<<<dim3(B * 2048), 256, 0, stream>>>(xk, kw);
  prep_v<<<dim3(64, B * H_HEADS), 256, 0, stream>>>(xv, vw);
  attn_fwd<<<dim3(B * H_HEADS * 32), 256, 0, stream>>>(xq, kw, vw, outp);  // 1024 blocks
}